// Round 7
// baseline (231.318 us; speedup 1.0000x reference)
//
#include <hip/hip_runtime.h>

// db2 coefficients (standard Daubechies-2, matches reference construction)
constexpr float h0 = 0.48296291314469025f;  // (1+√3)/(4√2)
constexpr float h1 = 0.83651630373746900f;  // (3+√3)/(4√2)
constexpr float h2 = 0.22414386804185735f;  // (3-√3)/(4√2)
constexpr float h3 = -0.12940952255092145f; // (1-√3)/(4√2)

// lpf = [h3,h2,h1,h0]; hpf = [-h0,h1,-h2,h3]
// Output row r = 2m+er taps orig rows m, min(m+1,511).
//   lpf vertical: er=0 -> (h2, h0); er=1 -> (h3, h1)
//   hpf vertical: er=0 -> (h1, h3); er=1 -> (-h0, -h2)
// Channels: c0,c1 = (lpf,lpf) [LH replicates source bug -> pre-summed];
// c2 = (lpf_h, hpf_w); c3 = (hpf_h, hpf_w); c2,c3 share horizontal hpf.
//
// V7: software-pipelined strip loop. V1-V6 lesson: one-shot waves (6 loads,
// full-latency stall, 2 stores, retire) sit at ~72 us regardless of pins/
// swizzle/NT -- the latency is structural. This version gives each thread a
// strip of 8 input rows: preload rows 0-2, then each iteration ISSUES row
// i+3's loads before computing output-pair i from rows (i,i+1). Loads run
// 3 iterations ahead of use (latency hidden inside the thread), vertical
// re-reads move entirely into registers (9 rows loaded / 8 consumed vs 2x),
// and VMEM instruction count drops 44%. Fully unrolled -> row[9][3] indices
// all static (stays in VGPRs, live set ~4 rows = 48 regs).

__global__ __launch_bounds__(256) void idwt_kernel(const float4* __restrict__ x,
                                                   float4* __restrict__ out) {
    const int idx = blockIdx.x * 256 + threadIdx.x;
    const int np = idx & 255;        // column-pair, consecutive within wave
    const int t  = idx >> 8;         // 0..2047
    const int s  = t & 63;           // row-strip (64 strips x 8 rows)
    const int b  = t >> 6;           // batch 0..31

    const int n0 = np << 1;
    const int n2 = (n0 + 2 < 512) ? n0 + 2 : 511;   // clamp only at np==255
    const int m0 = s << 3;                           // first input row of strip

    const size_t base = (size_t)(b << 9) * 512;

    float4 row[9][3];                // rows m0..m0+8; static indexing only

    // Preload rows 0..2 (m0+2 <= 506, no clamp possible here).
#pragma unroll
    for (int r = 0; r < 3; ++r) {
        const size_t ro = base + (size_t)(m0 + r) * 512;
        row[r][0] = x[ro + n0];
        row[r][1] = x[ro + n0 + 1];
        row[r][2] = x[ro + n2];
    }

    // Output: [B,1024,1024] fp32 = rows of 256 float4; iteration i writes
    // rows 2(m0+i), 2(m0+i)+1 at float4-col np.
    size_t o = ((size_t)(b << 10) + (size_t)(m0 << 1)) * 256 + np;

#pragma unroll
    for (int i = 0; i < 8; ++i) {
        // Stage 1: issue next row's loads (3 iterations ahead of its use).
        if (i < 6) {
            const int mr = m0 + i + 3;
            const int mm = (mr < 512) ? mr : 511;    // clamp (last strip, i==5)
            const size_t ro = base + (size_t)mm * 512;
            row[i + 3][0] = x[ro + n0];
            row[i + 3][1] = x[ro + n0 + 1];
            row[i + 3][2] = x[ro + n2];
        }

        // Stage 2: vertical then horizontal filter from rows i, i+1.
        float Lv0[3], Lv1[3], Hv0[3], Hv1[3];
#pragma unroll
        for (int j = 0; j < 3; ++j) {
            const float LA = row[i][j].x + row[i][j].y;
            const float LB = row[i + 1][j].x + row[i + 1][j].y;
            Lv0[j] = h2 * LA + h0 * LB;
            Lv1[j] = h3 * LA + h1 * LB;
            Hv0[j] = (h2 * row[i][j].z + h0 * row[i + 1][j].z)
                   + (h1 * row[i][j].w + h3 * row[i + 1][j].w);
            Hv1[j] = (h3 * row[i][j].z + h1 * row[i + 1][j].z)
                   + (-h0 * row[i][j].w - h2 * row[i + 1][j].w);
        }

        // horizontal: lpf ec=0 (h2,h0), ec=1 (h3,h1); hpf ec=0 (h1,h3), ec=1 (-h0,-h2)
        float4 r0, r1;
        r0.x = h2 * Lv0[0] + h0 * Lv0[1] + h1 * Hv0[0] + h3 * Hv0[1];
        r0.y = h3 * Lv0[0] + h1 * Lv0[1] - h0 * Hv0[0] - h2 * Hv0[1];
        r0.z = h2 * Lv0[1] + h0 * Lv0[2] + h1 * Hv0[1] + h3 * Hv0[2];
        r0.w = h3 * Lv0[1] + h1 * Lv0[2] - h0 * Hv0[1] - h2 * Hv0[2];
        r1.x = h2 * Lv1[0] + h0 * Lv1[1] + h1 * Hv1[0] + h3 * Hv1[1];
        r1.y = h3 * Lv1[0] + h1 * Lv1[1] - h0 * Hv1[0] - h2 * Hv1[1];
        r1.z = h2 * Lv1[1] + h0 * Lv1[2] + h1 * Hv1[1] + h3 * Hv1[2];
        r1.w = h3 * Lv1[1] + h1 * Lv1[2] - h0 * Hv1[1] - h2 * Hv1[2];

        out[o]       = r0;
        out[o + 256] = r1;
        o += 512;
    }
}

extern "C" void kernel_launch(void* const* d_in, const int* in_sizes, int n_in,
                              void* d_out, int out_size, void* d_ws, size_t ws_size,
                              hipStream_t stream) {
    const float4* x = (const float4*)d_in[0];
    float4* out = (float4*)d_out;
    // one thread per (b, strip, column-pair): 32 * 64 * 256 = 524288 threads
    const int blocks = 32 * 64 * 256 / 256;   // 2048
    idwt_kernel<<<blocks, 256, 0, stream>>>(x, out);
}